// Round 15
// baseline (243.800 us; speedup 1.0000x reference)
//
#include <hip/hip_runtime.h>

#define Himg 135
#define Wimg 240
#define Bimg 128
#define Cimg 3
#define BCN (Bimg*Cimg)
#define HW (Himg*Wimg)
#define CHW (Cimg*HW)
#define EPSF 1e-10f

typedef float fvec4 __attribute__((ext_vector_type(4)));
typedef _Float16 hf;
typedef hf h2 __attribute__((ext_vector_type(2)));
typedef hf h4v __attribute__((ext_vector_type(4)));
typedef hf h8 __attribute__((ext_vector_type(8)));
typedef float f4 __attribute__((ext_vector_type(4)));

// LDS map (hf units), 3-row-chunk layout:
//   Ar [64][72] @0, Ap @4608, Ht [16 cols][5 ch][RHP=72] @9216,
//   sred (12 f32 = 24 hf) @14976.  Total 30000 B -> 5 blocks/CU
//   (vs R14's 39.7KB/4 blocks — occupancy was the R14 limiter).
// ASTR=72: 144B row stride (16B-aligned for b128), 36 words == 4 mod 32
// -> 2-way bank alias max. RHP=72 likewise.
#define RSTG 64
#define ASTR 72
#define RHP  72
#define APOFF 4608
#define HTOFF 9216
#define SREDO 14976
#define LDSB  30000
#define CROWS 45          // output rows owned per chunk (3*45 >= OV_max 133)

__device__ __forceinline__ h2 pkrtz(float a, float b) {
  return __builtin_bit_cast(h2, __builtin_amdgcn_cvt_pkrtz(a, b));
}
__device__ __forceinline__ h4v pkrtz4(float a, float b, float c, float d) {
  h2 lo = pkrtz(a, b), hi = pkrtz(c, d);
  return (h4v){lo[0], lo[1], hi[0], hi[1]};
}

constexpr double cexp(double x) {
  double s = 1.0, t = 1.0;
  for (int i = 1; i < 48; ++i) { t *= x / (double)i; s += t; }
  return s;
}
template<int N>
struct GaussW {
  float inv, rsum;
  constexpr GaussW() : inv(0), rsum(0) {
    const float sig = (float)N / 5.0f;
    inv = 1.0f / (2.0f * sig * sig);
    float ssum = 0.f;
    for (int i = 0; i < N; ++i) {
      float d = (float)(i - N / 2);
      ssum += (float)cexp((double)(-(d * d) * inv));
    }
    rsum = 1.0f / ssum;
  }
};

// ws layout (floats): [0,384) num, [384,768) den, [768,896) per-image dots

// One scale over the staged strip: 3 col-tiles x (H-conv -> Ht -> V-conv).
// Strip-local row == chunk-local output row (hoff=0 by construction).
template<int N>
__device__ __forceinline__ void scale_pass(
    int OVc, int band, const hf* Ar, const hf* Ap, hf* Ht,
    int ln, int quad, int wave, float& numAcc, float& denAcc)
{
  constexpr int OW = Wimg - N + 1;
  constexpr GaussW<N> GW{};
  const int TILc = (OVc + 15) / 16;
  const int THTc = TILc + 1;                 // k-span cover; rows <= 64 ✓
  const f4 zf = {0.f, 0.f, 0.f, 0.f};

  // Toeplitz weight fragment w[k-ln], k=quad*8+j (tap d -> grid d-N/2).
  h8 wfrag;
  #pragma unroll
  for (int j = 0; j < 8; ++j) {
    const int di = quad * 8 + j - ln;
    const float fd = (float)(di - N / 2);
    float v = __expf(-(fd * fd) * GW.inv) * GW.rsum;
    v = ((unsigned)di < (unsigned)N) ? v : 0.f;
    wfrag[j] = (hf)v;
  }

  for (int ct = 0; ct < 3; ++ct) {
    __syncthreads();                         // Ht reuse / stage->H ordering
    // ---- H: A-frag straight from staged strip (one b128 per array) ----
    for (int t = wave; t < THTc; t += 4) {
      const int ao = (t * 16 + ln) * ASTR + ct * 16 + quad * 8;
      h8 ra = *(const h8*)(Ar + ao);
      h8 pa = *(const h8*)(Ap + ao);
      h8 rsq = ra * ra, psq = pa * pa, rp = ra * pa;
      f4 d0 = __builtin_amdgcn_mfma_f32_16x16x32_f16(ra,  wfrag, zf, 0, 0, 0);
      f4 d1 = __builtin_amdgcn_mfma_f32_16x16x32_f16(pa,  wfrag, zf, 0, 0, 0);
      f4 d2 = __builtin_amdgcn_mfma_f32_16x16x32_f16(rsq, wfrag, zf, 0, 0, 0);
      f4 d3 = __builtin_amdgcn_mfma_f32_16x16x32_f16(psq, wfrag, zf, 0, 0, 0);
      f4 d4 = __builtin_amdgcn_mfma_f32_16x16x32_f16(rp,  wfrag, zf, 0, 0, 0);
      hf* hb = Ht + (ln * 5) * RHP + t * 16 + quad * 4;
      *(h4v*)(hb + 0 * RHP) = pkrtz4(d0[0], d0[1], d0[2], d0[3]);
      *(h4v*)(hb + 1 * RHP) = pkrtz4(d1[0], d1[1], d1[2], d1[3]);
      *(h4v*)(hb + 2 * RHP) = pkrtz4(d2[0], d2[1], d2[2], d2[3]);
      *(h4v*)(hb + 3 * RHP) = pkrtz4(d3[0], d3[1], d3[2], d3[3]);
      *(h4v*)(hb + 4 * RHP) = pkrtz4(d4[0], d4[1], d4[2], d4[3]);
    }
    __syncthreads();
    // ---- V: B-frag = one ds_read_b128 per channel; pointwise on C ----
    const int ocol = band * 48 + ct * 16 + ln;
    for (int v = wave; v < TILc; v += 4) {
      const int j0 = v * 16;
      f4 C[5];
      #pragma unroll
      for (int c = 0; c < 5; ++c) {
        h8 bf = *(const h8*)(Ht + (ln * 5 + c) * RHP + j0 + quad * 8);
        C[c] = __builtin_amdgcn_mfma_f32_16x16x32_f16(wfrag, bf, zf, 0, 0, 0);
      }
      #pragma unroll
      for (int reg = 0; reg < 4; ++reg) {
        const int orow = j0 + quad * 4 + reg;      // chunk-local output row
        if (orow < OVc && ocol < OW) {
          float mu1 = C[0][reg], mu2 = C[1][reg];
          float sGT = fmaxf(C[2][reg] - mu1 * mu1, 0.f);
          float sP  = fmaxf(C[3][reg] - mu2 * mu2, 0.f);
          float sGP = C[4][reg] - mu1 * mu2;
          float g  = __fdividef(sGP, sGT + EPSF);
          float sv = sP - g * sGP;
          if (sGT < EPSF) { g = 0.f; sv = sP; sGT = 0.f; }
          if (sP  < EPSF) { g = 0.f; sv = 0.f; }
          if (g < 0.f)    { sv = sP; g = 0.f; }
          if (sv <= EPSF) sv = EPSF;
          numAcc += __log10f(1.f + __fdividef(g * g * sGT, sv + 2.0f));
          denAcc += __log10f(1.f + sGT * 0.5f);
        }
      }
    }
  }
}

// grid: 5760 blocks = 384 bc x 3 chunks x 5 bands, all identical type
__global__ __launch_bounds__(256, 5) void vif_fat_kernel(
    const float* __restrict__ recons, const float* __restrict__ xim,
    const float* __restrict__ Wl, float* __restrict__ ws)
{
  extern __shared__ hf lds[];
  hf* Ar = lds;
  hf* Ap = lds + APOFF;
  hf* Ht = lds + HTOFF;
  float* sred = (float*)(lds + SREDO);

  const int b     = blockIdx.x;
  const int band  = b % 5;
  const int rest  = b / 5;
  const int chunk = rest % 3;
  const int bc    = rest / 3;
  const int img   = bc / 3;
  const int tid   = threadIdx.x;
  const int lane  = tid & 63;
  const int ln    = lane & 15;
  const int quad  = lane >> 4;
  const int wave  = tid >> 6;
  const int r0s   = chunk * CROWS;           // first staged row == first output row

  const float* rb = recons + bc * HW;
  const float* pb = xim + bc * HW;
  const float* wb = Wl + (bc % 3) * HW;

  // ---- Stage 64x64(+halo) f16 strip + fused dot over owned partition ----
  // 512 items = exactly 2 per thread. Ownership: rows [45c,45c+45), cols
  // [band*48, +48) — every image pixel counted exactly once across blocks.
  float dotAcc = 0.f;
  for (int it = tid; it < RSTG * 8; it += 256) {
    const int row = it >> 3;
    const int c8  = it & 7;
    int grow = r0s + row;
    if (grow > Himg - 1) grow = Himg - 1;    // finite clamp (chunk2 tail rows;
                                             // only zero-weight/discarded taps)
    int gcol = band * 48 + c8 * 8;
    if (gcol > Wimg - 8) gcol = Wimg - 8;    // finite clamp (halo cols only)
    const int idx = grow * Wimg + gcol;
    fvec4 r0 = *(const fvec4*)(rb + idx);
    fvec4 r1 = *(const fvec4*)(rb + idx + 4);
    fvec4 p0 = *(const fvec4*)(pb + idx);
    fvec4 p1 = *(const fvec4*)(pb + idx + 4);
    h2 a0 = pkrtz(r0[0], r0[1]), a1 = pkrtz(r0[2], r0[3]);
    h2 a2 = pkrtz(r1[0], r1[1]), a3 = pkrtz(r1[2], r1[3]);
    h2 b0 = pkrtz(p0[0], p0[1]), b1 = pkrtz(p0[2], p0[3]);
    h2 b2 = pkrtz(p1[0], p1[1]), b3 = pkrtz(p1[2], p1[3]);
    *(h8*)(Ar + row * ASTR + c8 * 8) =
        (h8){a0[0], a0[1], a1[0], a1[1], a2[0], a2[1], a3[0], a3[1]};
    *(h8*)(Ap + row * ASTR + c8 * 8) =
        (h8){b0[0], b0[1], b1[0], b1[1], b2[0], b2[1], b3[0], b3[1]};
    // owned rows are never clamped (row<45 => grow<=134)
    if (c8 < 6 && row < CROWS) {
      fvec4 w0 = *(const fvec4*)(wb + idx);
      fvec4 w1 = *(const fvec4*)(wb + idx + 4);
      dotAcc += (p0[0]-r0[0])*w0[0] + (p0[1]-r0[1])*w0[1]
              + (p0[2]-r0[2])*w0[2] + (p0[3]-r0[3])*w0[3]
              + (p1[0]-r1[0])*w1[0] + (p1[1]-r1[1])*w1[1]
              + (p1[2]-r1[2])*w1[2] + (p1[3]-r1[3])*w1[3];
    }
  }

  // ---- all 4 scales from the same staged strip ----
  // OVc = clamp(OV_N - chunk*45, 0, 45); all values > 0 for every scale.
  float numAcc = 0.f, denAcc = 0.f;
  {
    const int base = chunk * CROWS;
    int ovc;
    ovc = (Himg - 17 + 1) - base; if (ovc > CROWS) ovc = CROWS;
    scale_pass<17>(ovc, band, Ar, Ap, Ht, ln, quad, wave, numAcc, denAcc);
    ovc = (Himg - 9 + 1) - base;  if (ovc > CROWS) ovc = CROWS;
    scale_pass< 9>(ovc, band, Ar, Ap, Ht, ln, quad, wave, numAcc, denAcc);
    ovc = (Himg - 5 + 1) - base;  if (ovc > CROWS) ovc = CROWS;
    scale_pass< 5>(ovc, band, Ar, Ap, Ht, ln, quad, wave, numAcc, denAcc);
    ovc = (Himg - 3 + 1) - base;  if (ovc > CROWS) ovc = CROWS;
    scale_pass< 3>(ovc, band, Ar, Ap, Ht, ln, quad, wave, numAcc, denAcc);
  }

  // ---- block reduction (num, den, dot) ----
  #pragma unroll
  for (int off = 32; off > 0; off >>= 1) {
    numAcc += __shfl_down(numAcc, off);
    denAcc += __shfl_down(denAcc, off);
    dotAcc += __shfl_down(dotAcc, off);
  }
  __syncthreads();
  if (lane == 0) {
    sred[wave] = numAcc; sred[4 + wave] = denAcc; sred[8 + wave] = dotAcc;
  }
  __syncthreads();
  if (tid == 0) {
    atomicAdd(&ws[bc],        sred[0] + sred[1] + sred[2] + sred[3]);
    atomicAdd(&ws[384 + bc],  sred[4] + sred[5] + sred[6] + sred[7]);
    atomicAdd(&ws[768 + img], sred[8] + sred[9] + sred[10] + sred[11]);
  }
}

__global__ __launch_bounds__(128) void finalize_kernel(
    const float* __restrict__ ws, float* __restrict__ out)
{
  __shared__ float s1[128], s2[128];
  const int t = threadIdx.x;
  float d = ws[768 + t];
  float psq = d * d;
  float vimg = 0.f;
  #pragma unroll
  for (int c = 0; c < 3; ++c) {
    int bc = t * 3 + c;
    vimg += ws[bc] / ws[384 + bc];
  }
  float rl = 1.f - vimg * (1.f / 3.f);
  s1[t] = psq; s2[t] = rl;
  __syncthreads();
  for (int off = 64; off > 0; off >>= 1) {
    if (t < off) { s1[t] += s1[t + off]; s2[t] += s2[t + off]; }
    __syncthreads();
  }
  if (t == 0) {
    float pred = s1[0] * (1.f / 128.f);
    float rec  = s2[0] * (1.f / 128.f);
    out[0] = pred + rec;
    out[1] = rec;
    out[2] = pred;
  }
}

extern "C" void kernel_launch(void* const* d_in, const int* in_sizes, int n_in,
                              void* d_out, int out_size, void* d_ws, size_t ws_size,
                              hipStream_t stream) {
  const float* recons = (const float*)d_in[0];
  const float* x      = (const float*)d_in[1];
  const float* Wl     = (const float*)d_in[2];
  float* ws  = (float*)d_ws;
  float* out = (float*)d_out;

  hipMemsetAsync(d_ws, 0, 896 * sizeof(float), stream);

  vif_fat_kernel<<<BCN * 3 * 5, 256, LDSB, stream>>>(recons, x, Wl, ws);

  finalize_kernel<<<1, 128, 0, stream>>>(ws, out);
}

// Round 16
// 207.782 us; speedup vs baseline: 1.1733x; 1.1733x over previous
//
#include <hip/hip_runtime.h>

#define Himg 135
#define Wimg 240
#define Bimg 128
#define Cimg 3
#define BCN (Bimg*Cimg)
#define HW (Himg*Wimg)
#define CHW (Cimg*HW)
#define EPSF 1e-10f

typedef float fvec4 __attribute__((ext_vector_type(4)));
typedef _Float16 hf;
typedef hf h2 __attribute__((ext_vector_type(2)));
typedef hf h4v __attribute__((ext_vector_type(4)));
typedef hf h8 __attribute__((ext_vector_type(8)));
typedef float f4 __attribute__((ext_vector_type(4)));

// R14 geometry (best measured): 2 row-chunks, 5 col-bands, 4 blocks/CU.
// LDS map (hf units): Ar [77][72] @0, Ap @5760, Ht [16][5][104] @11520,
// sred @19840. Total 39728 B.
#define RSTG 77
#define ASTR 72
#define RHP  104
#define APOFF 5760
#define HTOFF 11520
#define SREDO 19840
#define LDSB  39728

__device__ __forceinline__ h2 pkrtz(float a, float b) {
  return __builtin_bit_cast(h2, __builtin_amdgcn_cvt_pkrtz(a, b));
}
__device__ __forceinline__ h4v pkrtz4(float a, float b, float c, float d) {
  h2 lo = pkrtz(a, b), hi = pkrtz(c, d);
  return (h4v){lo[0], lo[1], hi[0], hi[1]};
}

constexpr double cexp(double x) {
  double s = 1.0, t = 1.0;
  for (int i = 1; i < 48; ++i) { t *= x / (double)i; s += t; }
  return s;
}
template<int N>
struct GaussW {
  float inv, rsum;
  constexpr GaussW() : inv(0), rsum(0) {
    const float sig = (float)N / 5.0f;
    inv = 1.0f / (2.0f * sig * sig);
    float ssum = 0.f;
    for (int i = 0; i < N; ++i) {
      float d = (float)(i - N / 2);
      ssum += (float)cexp((double)(-(d * d) * inv));
    }
    rsum = 1.0f / ssum;
  }
};

// ws layout (floats): [0,384) num, [384,768) den, [768,896) per-image dots

template<int N>
__device__ __forceinline__ void scale_pass(
    int chunk, int band, const hf* Ar, const hf* Ap, hf* Ht,
    int ln, int quad, int wave, float& numAcc, float& denAcc)
{
  constexpr int OW  = Wimg - N + 1;
  constexpr int OV  = Himg - N + 1;
  constexpr int OV0 = (OV + 1) / 2;
  constexpr GaussW<N> GW{};

  const int OVc  = chunk ? (OV - OV0) : OV0;
  const int TILc = (OVc + 15) / 16;
  const int THTc = TILc + 1;
  const int hoff = chunk ? (OV0 - 58) : 0;   // staged-local row of tap 0
  const f4 zf = {0.f, 0.f, 0.f, 0.f};

  // Toeplitz weight fragment w[k-ln], k=quad*8+j (tap d -> grid d-N/2).
  h8 wfrag;
  #pragma unroll
  for (int j = 0; j < 8; ++j) {
    const int di = quad * 8 + j - ln;
    const float fd = (float)(di - N / 2);
    float v = __expf(-(fd * fd) * GW.inv) * GW.rsum;
    v = ((unsigned)di < (unsigned)N) ? v : 0.f;
    wfrag[j] = (hf)v;
  }

  for (int ct = 0; ct < 3; ++ct) {
    __syncthreads();                         // Ht reuse / stage->H ordering
    // ---- H: A-frag from staged LDS (one ds_read_b128 per array) ----
    for (int t = wave; t < THTc; t += 4) {
      int rowL = hoff + t * 16 + ln;
      if (rowL > RSTG - 1) rowL = RSTG - 1;  // finite clamp; masked by 0-weights
      const int ao = rowL * ASTR + ct * 16 + quad * 8;
      h8 ra = *(const h8*)(Ar + ao);
      h8 pa = *(const h8*)(Ap + ao);
      h8 rsq = ra * ra, psq = pa * pa, rp = ra * pa;
      f4 d0 = __builtin_amdgcn_mfma_f32_16x16x32_f16(ra,  wfrag, zf, 0, 0, 0);
      f4 d1 = __builtin_amdgcn_mfma_f32_16x16x32_f16(pa,  wfrag, zf, 0, 0, 0);
      f4 d2 = __builtin_amdgcn_mfma_f32_16x16x32_f16(rsq, wfrag, zf, 0, 0, 0);
      f4 d3 = __builtin_amdgcn_mfma_f32_16x16x32_f16(psq, wfrag, zf, 0, 0, 0);
      f4 d4 = __builtin_amdgcn_mfma_f32_16x16x32_f16(rp,  wfrag, zf, 0, 0, 0);
      hf* hb = Ht + (ln * 5) * RHP + t * 16 + quad * 4;
      *(h4v*)(hb + 0 * RHP) = pkrtz4(d0[0], d0[1], d0[2], d0[3]);
      *(h4v*)(hb + 1 * RHP) = pkrtz4(d1[0], d1[1], d1[2], d1[3]);
      *(h4v*)(hb + 2 * RHP) = pkrtz4(d2[0], d2[1], d2[2], d2[3]);
      *(h4v*)(hb + 3 * RHP) = pkrtz4(d3[0], d3[1], d3[2], d3[3]);
      *(h4v*)(hb + 4 * RHP) = pkrtz4(d4[0], d4[1], d4[2], d4[3]);
    }
    __syncthreads();
    // ---- V: B-frag = one ds_read_b128 per channel; pointwise on C ----
    // Algebraic rewrite (one rcp, log-of-product):
    //   g^2*sGT/(sv+2) == t1*sGT / (A*((sP+2)*A - t1)),  A=sGT+eps, t1=sGP^2
    //   sum log10(f_i) == log10(prod f_i); factors in [1,~1.2] -> safe.
    const int ocol = band * 48 + ct * 16 + ln;
    const bool colv = ocol < OW;
    for (int v = wave; v < TILc; v += 4) {
      const int j0 = v * 16;
      f4 C[5];
      #pragma unroll
      for (int c = 0; c < 5; ++c) {
        h8 bf = *(const h8*)(Ht + (ln * 5 + c) * RHP + j0 + quad * 8);
        C[c] = __builtin_amdgcn_mfma_f32_16x16x32_f16(wfrag, bf, zf, 0, 0, 0);
      }
      float numP = 1.f, denP = 1.f;
      #pragma unroll
      for (int reg = 0; reg < 4; ++reg) {
        const int orow = j0 + quad * 4 + reg;
        const bool inb = (orow < OVc) && colv;
        float mu1 = C[0][reg], mu2 = C[1][reg];
        float sGT = fmaxf(C[2][reg] - mu1 * mu1, 0.f);
        float sP  = fmaxf(C[3][reg] - mu2 * mu2, 0.f);
        float sGP = C[4][reg] - mu1 * mu2;
        float A   = sGT + EPSF;
        float t1  = sGP * sGP;
        float D   = A * fmaf(sP + 2.f, A, -t1);
        float numf = 1.f + __fdividef(t1 * sGT, D);
        const bool valid = inb && (fminf(sGT, sP) >= EPSF) && (sGP > 0.f);
        numf = valid ? numf : 1.f;
        float denf = inb ? fmaf(sGT, 0.5f, 1.f) : 1.f;
        numP *= numf;
        denP *= denf;
      }
      numAcc += __log10f(numP);
      denAcc += __log10f(denP);
    }
  }
}

// grid: 3840 blocks = 384 bc x 2 chunks x 5 bands, all identical type
__global__ __launch_bounds__(256, 4) void vif_fat_kernel(
    const float* __restrict__ recons, const float* __restrict__ xim,
    const float* __restrict__ Wl, float* __restrict__ ws)
{
  extern __shared__ hf lds[];
  hf* Ar = lds;
  hf* Ap = lds + APOFF;
  hf* Ht = lds + HTOFF;
  float* sred = (float*)(lds + SREDO);

  const int b     = blockIdx.x;
  const int band  = b % 5;
  const int rest  = b / 5;
  const int chunk = rest & 1;
  const int bc    = rest >> 1;
  const int img   = bc / 3;
  const int tid   = threadIdx.x;
  const int lane  = tid & 63;
  const int ln    = lane & 15;
  const int quad  = lane >> 4;
  const int wave  = tid >> 6;
  const int r0s   = chunk ? 58 : 0;          // first staged row

  const float* rb = recons + bc * HW;
  const float* pb = xim + bc * HW;
  const float* wb = Wl + (bc % 3) * HW;

  // ---- Stage 77x64 f16 strip + fused dot over owned partition ----
  float dotAcc = 0.f;
  for (int it = tid; it < RSTG * 8; it += 256) {
    const int row = it >> 3;
    const int c8  = it & 7;
    const int grow = r0s + row;
    int gcol = band * 48 + c8 * 8;
    if (gcol > Wimg - 8) gcol = Wimg - 8;    // finite clamp (halo cols only)
    const int idx = grow * Wimg + gcol;
    fvec4 r0 = *(const fvec4*)(rb + idx);
    fvec4 r1 = *(const fvec4*)(rb + idx + 4);
    fvec4 p0 = *(const fvec4*)(pb + idx);
    fvec4 p1 = *(const fvec4*)(pb + idx + 4);
    h2 a0 = pkrtz(r0[0], r0[1]), a1 = pkrtz(r0[2], r0[3]);
    h2 a2 = pkrtz(r1[0], r1[1]), a3 = pkrtz(r1[2], r1[3]);
    h2 b0 = pkrtz(p0[0], p0[1]), b1 = pkrtz(p0[2], p0[3]);
    h2 b2 = pkrtz(p1[0], p1[1]), b3 = pkrtz(p1[2], p1[3]);
    *(h8*)(Ar + row * ASTR + c8 * 8) =
        (h8){a0[0], a0[1], a1[0], a1[1], a2[0], a2[1], a3[0], a3[1]};
    *(h8*)(Ap + row * ASTR + c8 * 8) =
        (h8){b0[0], b0[1], b1[0], b1[1], b2[0], b2[1], b3[0], b3[1]};
    const bool rowOwned = chunk ? (grow >= 68) : (grow < 68);
    if (c8 < 6 && rowOwned) {                // owned cols never clamped
      fvec4 w0 = *(const fvec4*)(wb + idx);
      fvec4 w1 = *(const fvec4*)(wb + idx + 4);
      dotAcc += (p0[0]-r0[0])*w0[0] + (p0[1]-r0[1])*w0[1]
              + (p0[2]-r0[2])*w0[2] + (p0[3]-r0[3])*w0[3]
              + (p1[0]-r1[0])*w1[0] + (p1[1]-r1[1])*w1[1]
              + (p1[2]-r1[2])*w1[2] + (p1[3]-r1[3])*w1[3];
    }
  }

  // ---- all 4 scales from the same staged strip ----
  float numAcc = 0.f, denAcc = 0.f;
  scale_pass<17>(chunk, band, Ar, Ap, Ht, ln, quad, wave, numAcc, denAcc);
  scale_pass< 9>(chunk, band, Ar, Ap, Ht, ln, quad, wave, numAcc, denAcc);
  scale_pass< 5>(chunk, band, Ar, Ap, Ht, ln, quad, wave, numAcc, denAcc);
  scale_pass< 3>(chunk, band, Ar, Ap, Ht, ln, quad, wave, numAcc, denAcc);

  // ---- block reduction (num, den, dot) ----
  #pragma unroll
  for (int off = 32; off > 0; off >>= 1) {
    numAcc += __shfl_down(numAcc, off);
    denAcc += __shfl_down(denAcc, off);
    dotAcc += __shfl_down(dotAcc, off);
  }
  __syncthreads();
  if (lane == 0) {
    sred[wave] = numAcc; sred[4 + wave] = denAcc; sred[8 + wave] = dotAcc;
  }
  __syncthreads();
  if (tid == 0) {
    atomicAdd(&ws[bc],        sred[0] + sred[1] + sred[2] + sred[3]);
    atomicAdd(&ws[384 + bc],  sred[4] + sred[5] + sred[6] + sred[7]);
    atomicAdd(&ws[768 + img], sred[8] + sred[9] + sred[10] + sred[11]);
  }
}

__global__ __launch_bounds__(128) void finalize_kernel(
    const float* __restrict__ ws, float* __restrict__ out)
{
  __shared__ float s1[128], s2[128];
  const int t = threadIdx.x;
  float d = ws[768 + t];
  float psq = d * d;
  float vimg = 0.f;
  #pragma unroll
  for (int c = 0; c < 3; ++c) {
    int bc = t * 3 + c;
    vimg += ws[bc] / ws[384 + bc];
  }
  float rl = 1.f - vimg * (1.f / 3.f);
  s1[t] = psq; s2[t] = rl;
  __syncthreads();
  for (int off = 64; off > 0; off >>= 1) {
    if (t < off) { s1[t] += s1[t + off]; s2[t] += s2[t + off]; }
    __syncthreads();
  }
  if (t == 0) {
    float pred = s1[0] * (1.f / 128.f);
    float rec  = s2[0] * (1.f / 128.f);
    out[0] = pred + rec;
    out[1] = rec;
    out[2] = pred;
  }
}

extern "C" void kernel_launch(void* const* d_in, const int* in_sizes, int n_in,
                              void* d_out, int out_size, void* d_ws, size_t ws_size,
                              hipStream_t stream) {
  const float* recons = (const float*)d_in[0];
  const float* x      = (const float*)d_in[1];
  const float* Wl     = (const float*)d_in[2];
  float* ws  = (float*)d_ws;
  float* out = (float*)d_out;

  hipMemsetAsync(d_ws, 0, 896 * sizeof(float), stream);

  vif_fat_kernel<<<BCN * 2 * 5, 256, LDSB, stream>>>(recons, x, Wl, ws);

  finalize_kernel<<<1, 128, 0, stream>>>(ws, out);
}